// Round 1
// baseline (2262.934 us; speedup 1.0000x reference)
//
#include <hip/hip_runtime.h>
#include <cmath>

// Problem dims
#define S 96
#define B 32
#define I 64
#define H 256
#define ROWS (S*B)            // 3072 independent (s,b) rows
#define M 6                   // rows per block in recurrence -> 512 blocks (2/CU)
#define NBLK (ROWS/M)

// ws layout (floats): fx | cx | Wt_fh | Wt_ch  (~6.8 MB total)
#define FX_OFF  0
#define CX_OFF  (ROWS*H)
#define WTF_OFF (2*ROWS*H)
#define WTC_OFF (2*ROWS*H + H*H)

// fx[row][k] = sum_i x[row][i]*W_fx[k][i] + b_fx[k]; same for cx with W_cx/b_cx.
// One block per row (3072 blocks), thread k = output column.
__global__ void proj_kernel(const float* __restrict__ x,
                            const float* __restrict__ W_fx, const float* __restrict__ b_fx,
                            const float* __restrict__ W_cx, const float* __restrict__ b_cx,
                            float* __restrict__ fx, float* __restrict__ cx)
{
    const int row = blockIdx.x;
    const int k = threadIdx.x;
    __shared__ float xs[I];
    if (k < I) xs[k] = x[row*I + k];
    __syncthreads();
    const float4* wf = reinterpret_cast<const float4*>(W_fx + k*I);
    const float4* wc = reinterpret_cast<const float4*>(W_cx + k*I);
    float af = 0.f, ac = 0.f;
#pragma unroll
    for (int i = 0; i < I/4; ++i) {
        float4 a = wf[i];
        float4 b = wc[i];
        const float* xp = &xs[i*4];
        af = fmaf(a.x, xp[0], fmaf(a.y, xp[1], fmaf(a.z, xp[2], fmaf(a.w, xp[3], af))));
        ac = fmaf(b.x, xp[0], fmaf(b.y, xp[1], fmaf(b.z, xp[2], fmaf(b.w, xp[3], ac))));
    }
    fx[row*H + k] = af + b_fx[k];
    cx[row*H + k] = ac + b_cx[k];
}

// Repack W[k][h] (256x256) -> Wt[(h/4)*1024 + k*4 + (h%3? no: h&3)] so that the
// recurrence's thread k loads 4 consecutive-h weights for its column as one
// coalesced float4 at Wt[h4*H + 4*k].
__global__ void transpose_kernel(const float* __restrict__ W_fh, const float* __restrict__ W_ch,
                                 float* __restrict__ Wtf, float* __restrict__ Wtc)
{
    const int idx = blockIdx.x * blockDim.x + threadIdx.x;   // 0..65535
    const int kcol = idx & (H-1);
    const int h = idx >> 8;
    const int dst = (h >> 2) * (H*4) + kcol*4 + (h & 3);
    Wtf[dst] = W_fh[kcol*H + h];
    Wtc[dst] = W_ch[kcol*H + h];
}

// Recurrence: each block owns M consecutive rows for all 96 steps.
// h state in LDS (broadcast float4 reads), c + accumulators in registers.
__global__ void __launch_bounds__(H, 2)
lstm_rec_kernel(const float* __restrict__ fx, const float* __restrict__ cx,
                const float* __restrict__ Wtf, const float* __restrict__ Wtc,
                const float* __restrict__ b_fh, const float* __restrict__ b_ch,
                float* __restrict__ out)
{
    const int k = threadIdx.x;
    const int r0 = blockIdx.x * M;
    __shared__ __align__(16) float hbuf[M][H];
    float cc[M], cxr[M];
    const float bfh = b_fh[k];
    const float bch = b_ch[k];
#pragma unroll
    for (int r = 0; r < M; ++r) {
        cc[r] = 0.f;
        hbuf[r][k] = 0.f;
        cxr[r] = cx[(r0 + r)*H + k];
    }
    __syncthreads();

    float* hseq = out;
    float* hfin = out + (size_t)S*ROWS*H;
    float* cfin = hfin + (size_t)ROWS*H;

    for (int t = 0; t < S; ++t) {
        float accf[M], accc[M];
#pragma unroll
        for (int r = 0; r < M; ++r) { accf[r] = 0.f; accc[r] = 0.f; }

        for (int h4 = 0; h4 < H; h4 += 4) {
            float4 wf = *reinterpret_cast<const float4*>(&Wtf[h4*H + 4*k]);
            float4 wc = *reinterpret_cast<const float4*>(&Wtc[h4*H + 4*k]);
#pragma unroll
            for (int r = 0; r < M; ++r) {
                float4 hv = *reinterpret_cast<const float4*>(&hbuf[r][h4]);
                accf[r] = fmaf(hv.x, wf.x, fmaf(hv.y, wf.y, fmaf(hv.z, wf.z, fmaf(hv.w, wf.w, accf[r]))));
                accc[r] = fmaf(hv.x, wc.x, fmaf(hv.y, wc.y, fmaf(hv.z, wc.z, fmaf(hv.w, wc.w, accc[r]))));
            }
        }
        __syncthreads();   // all reads of hbuf done before overwrite

#pragma unroll
        for (int r = 0; r < M; ++r) {
            const int rr = r0 + r;
            const int b = rr & (B-1);
            const float zf = fx[(t*B + b)*H + k] + accf[r] + bfh;   // gate pre-activation
            const float g = 1.f / (1.f + expf(-zf));
            const float zc = cxr[r] + accc[r] + bch;                // candidate pre-activation
            const float cand = tanhf(zc);
            const float c2 = g * (cc[r] + cand);                    // cc = g*cc + g*cand
            cc[r] = c2;
            const float hn = g * tanhf(c2);
            hbuf[r][k] = hn;
            hseq[((size_t)t*ROWS + rr)*H + k] = hn;
        }
        __syncthreads();   // writes visible before next step's reads
    }

#pragma unroll
    for (int r = 0; r < M; ++r) {
        hfin[(r0 + r)*H + k] = hbuf[r][k];
        cfin[(r0 + r)*H + k] = cc[r];
    }
}

extern "C" void kernel_launch(void* const* d_in, const int* in_sizes, int n_in,
                              void* d_out, int out_size, void* d_ws, size_t ws_size,
                              hipStream_t stream)
{
    const float* x    = (const float*)d_in[0];
    const float* W_fx = (const float*)d_in[1];
    const float* b_fx = (const float*)d_in[2];
    const float* W_fh = (const float*)d_in[3];
    const float* b_fh = (const float*)d_in[4];
    const float* W_cx = (const float*)d_in[5];
    const float* b_cx = (const float*)d_in[6];
    const float* W_ch = (const float*)d_in[7];
    const float* b_ch = (const float*)d_in[8];
    float* out = (float*)d_out;
    float* ws  = (float*)d_ws;

    float* fx  = ws + FX_OFF;
    float* cx  = ws + CX_OFF;
    float* Wtf = ws + WTF_OFF;
    float* Wtc = ws + WTC_OFF;

    hipLaunchKernelGGL(proj_kernel, dim3(ROWS), dim3(H), 0, stream,
                       x, W_fx, b_fx, W_cx, b_cx, fx, cx);
    hipLaunchKernelGGL(transpose_kernel, dim3(H*H/256), dim3(256), 0, stream,
                       W_fh, W_ch, Wtf, Wtc);
    hipLaunchKernelGGL(lstm_rec_kernel, dim3(NBLK), dim3(H), 0, stream,
                       fx, cx, Wtf, Wtc, b_fh, b_ch, out);
}

// Round 2
// 1520.335 us; speedup vs baseline: 1.4884x; 1.4884x over previous
//
#include <hip/hip_runtime.h>
#include <cmath>

// Problem dims
#define S 96
#define BB 32
#define II 64
#define H 256
#define ROWS (S*BB)         // 3072 independent (s,b) rows
#define R 32                // rows per block (all same b, s-chunk of 32)
#define NB (ROWS/R)         // 96 blocks
#define PADK 264            // LDS row stride in bf16 elems (+8 pad, 16B-aligned rows)

// ws float layout: fx | cx | weight-fragment region (ushort)
#define FX_OFF 0
#define CX_OFF (ROWS*H)
#define WREP_OFF (2*ROWS*H)   // byte-offset 6291456, 16B aligned

typedef __attribute__((ext_vector_type(8))) short bf16x8;   // 8 bf16 = 4 VGPRs
typedef __attribute__((ext_vector_type(4))) float f32x4;
typedef unsigned short ushort_t;
typedef unsigned int uint_t;

__device__ __host__ inline ushort_t f2bf(float f){
    uint_t u = __float_as_uint(f);
    u += 0x7FFF + ((u >> 16) & 1);            // RNE
    return (ushort_t)(u >> 16);
}
__device__ inline float bf2f(ushort_t h){ return __uint_as_float(((uint_t)h) << 16); }

// ---------------- prep 1: input projections (fp32) ----------------
__global__ void proj_kernel(const float* __restrict__ x,
                            const float* __restrict__ W_fx, const float* __restrict__ b_fx,
                            const float* __restrict__ W_cx, const float* __restrict__ b_cx,
                            float* __restrict__ fx, float* __restrict__ cx)
{
    const int row = blockIdx.x;
    const int k = threadIdx.x;
    __shared__ float xs[II];
    if (k < II) xs[k] = x[row*II + k];
    __syncthreads();
    const float4* wf = reinterpret_cast<const float4*>(W_fx + k*II);
    const float4* wc = reinterpret_cast<const float4*>(W_cx + k*II);
    float af = 0.f, ac = 0.f;
#pragma unroll
    for (int i = 0; i < II/4; ++i) {
        float4 a = wf[i];
        float4 b = wc[i];
        const float* xp = &xs[i*4];
        af = fmaf(a.x, xp[0], fmaf(a.y, xp[1], fmaf(a.z, xp[2], fmaf(a.w, xp[3], af))));
        ac = fmaf(b.x, xp[0], fmaf(b.y, xp[1], fmaf(b.z, xp[2], fmaf(b.w, xp[3], ac))));
    }
    fx[row*H + k] = af + b_fx[k];
    cx[row*H + k] = ac + b_cx[k];
}

// ---------------- prep 2: split weights to bf16 hi/lo in MFMA B-fragment order --
// B[k][n] = W[n][k].  Fragment element (lane,j) of tile (nt,kt):
//   n = nt*16 + (lane&15), k = kt*32 + (lane>>4)*8 + j
// dst = ((nt*8 + kt)*64 + lane)*8 + j
// Region: Wf_hi | Wf_lo | Wc_hi | Wc_lo, each 65536 ushort.
__global__ void repack_kernel(const float* __restrict__ Wf, const float* __restrict__ Wc,
                              ushort_t* __restrict__ wr)
{
    const int idx = blockIdx.x*256 + threadIdx.x;   // 0..65535
    const int n = idx >> 8, k = idx & 255;
    const int lane = (((k >> 3) & 3) << 4) | (n & 15);
    const int dst = ((((n >> 4)*8 + (k >> 5))*64) + lane)*8 + (k & 7);
    float f = Wf[n*H + k];
    ushort_t h = f2bf(f);
    wr[dst] = h;
    wr[65536 + dst] = f2bf(f - bf2f(h));
    float c = Wc[n*H + k];
    ushort_t hc = f2bf(c);
    wr[131072 + dst] = hc;
    wr[196608 + dst] = f2bf(c - bf2f(hc));
}

// ---------------- main: MFMA recurrence ----------------
// Block = (b, s-chunk): 32 rows, 512 threads = 8 waves.
// Wave w owns output cols [32w, 32w+32) of BOTH gates (2 nt tiles each) so the
// elementwise update is register-local. 3-term split-bf16 MFMA for fp32-level
// precision. Weights streamed from L2 in fragment order each step.
__global__ __launch_bounds__(512, 2) void lstm_mfma_kernel(
    const float* __restrict__ fx, const float* __restrict__ cx,
    const ushort_t* __restrict__ wr,
    const float* __restrict__ b_fh, const float* __restrict__ b_ch,
    float* __restrict__ out)
{
    const int tid = threadIdx.x;
    const int w = tid >> 6, lane = tid & 63;
    const int m = lane & 15, q = lane >> 4;
    const int b = blockIdx.x & 31;
    const int s0 = (blockIdx.x >> 5) * R;

    __shared__ ushort_t hhi[R][PADK];
    __shared__ ushort_t hlo[R][PADK];

    for (int i = tid; i < R*PADK; i += 512) { (&hhi[0][0])[i] = 0; (&hlo[0][0])[i] = 0; }

    const ushort_t* wfh = wr;
    const ushort_t* wfl = wr + 65536;
    const ushort_t* wch = wr + 131072;
    const ushort_t* wcl = wr + 196608;

    int col[2]; col[0] = w*32 + m; col[1] = col[0] + 16;
    float bfh[2], bch[2];
    float cxr[2][2][4];
    f32x4 cst[2][2];
#pragma unroll
    for (int n = 0; n < 2; ++n) { bfh[n] = b_fh[col[n]]; bch[n] = b_ch[col[n]]; }
#pragma unroll
    for (int rt = 0; rt < 2; ++rt)
#pragma unroll
        for (int n = 0; n < 2; ++n) {
            cst[rt][n] = (f32x4){0.f, 0.f, 0.f, 0.f};
#pragma unroll
            for (int reg = 0; reg < 4; ++reg) {
                const int rl = rt*16 + q*4 + reg;
                cxr[rt][n][reg] = cx[((s0 + rl)*BB + b)*H + col[n]];
            }
        }
    __syncthreads();

    float* hseq = out;
    float* hfin = out + (size_t)S*ROWS*H;
    float* cfin = hfin + (size_t)ROWS*H;

    for (int t = 0; t < S; ++t) {
        f32x4 accF[2][2], accC[2][2];
#pragma unroll
        for (int rt = 0; rt < 2; ++rt)
#pragma unroll
            for (int n = 0; n < 2; ++n) {
                accF[rt][n] = (f32x4){0.f, 0.f, 0.f, 0.f};
                accC[rt][n] = (f32x4){0.f, 0.f, 0.f, 0.f};
            }

#pragma unroll
        for (int kt = 0; kt < 8; ++kt) {
            bf16x8 aH[2], aL[2];
#pragma unroll
            for (int rt = 0; rt < 2; ++rt) {
                aH[rt] = *(const bf16x8*)&hhi[rt*16 + m][kt*32 + q*8];
                aL[rt] = *(const bf16x8*)&hlo[rt*16 + m][kt*32 + q*8];
            }
#pragma unroll
            for (int n = 0; n < 2; ++n) {
                const int nt = w*2 + n;
                const int fo = ((nt*8 + kt)*64 + lane)*8;
                bf16x8 bFH = *(const bf16x8*)&wfh[fo];
                bf16x8 bFL = *(const bf16x8*)&wfl[fo];
                bf16x8 bCH = *(const bf16x8*)&wch[fo];
                bf16x8 bCL = *(const bf16x8*)&wcl[fo];
#pragma unroll
                for (int rt = 0; rt < 2; ++rt) {
                    accF[rt][n] = __builtin_amdgcn_mfma_f32_16x16x32_bf16(aH[rt], bFH, accF[rt][n], 0, 0, 0);
                    accF[rt][n] = __builtin_amdgcn_mfma_f32_16x16x32_bf16(aL[rt], bFH, accF[rt][n], 0, 0, 0);
                    accF[rt][n] = __builtin_amdgcn_mfma_f32_16x16x32_bf16(aH[rt], bFL, accF[rt][n], 0, 0, 0);
                    accC[rt][n] = __builtin_amdgcn_mfma_f32_16x16x32_bf16(aH[rt], bCH, accC[rt][n], 0, 0, 0);
                    accC[rt][n] = __builtin_amdgcn_mfma_f32_16x16x32_bf16(aL[rt], bCH, accC[rt][n], 0, 0, 0);
                    accC[rt][n] = __builtin_amdgcn_mfma_f32_16x16x32_bf16(aH[rt], bCL, accC[rt][n], 0, 0, 0);
                }
            }
        }
        __syncthreads();   // all waves done reading hhi/hlo before overwrite

        const float* fxt = fx + (t*BB + b)*H;
        float fxv[2] = { fxt[col[0]], fxt[col[1]] };
#pragma unroll
        for (int rt = 0; rt < 2; ++rt)
#pragma unroll
            for (int n = 0; n < 2; ++n) {
#pragma unroll
                for (int reg = 0; reg < 4; ++reg) {
                    const int rl = rt*16 + q*4 + reg;
                    const float zf = accF[rt][n][reg] + fxv[n] + bfh[n];
                    const float g = 1.f / (1.f + __expf(-zf));
                    const float zc = accC[rt][n][reg] + cxr[rt][n][reg] + bch[n];
                    const float cand = 1.f - 2.f / (1.f + __expf(2.f*zc));   // tanh
                    const float cn = g * (cst[rt][n][reg] + cand);
                    cst[rt][n][reg] = cn;
                    const float hn = g * (1.f - 2.f / (1.f + __expf(2.f*cn)));
                    hseq[(((size_t)t*S + (s0 + rl))*BB + b)*H + col[n]] = hn;
                    const ushort_t hi = f2bf(hn);
                    hhi[rl][col[n]] = hi;
                    hlo[rl][col[n]] = f2bf(hn - bf2f(hi));
                    if (t == S-1) {
                        hfin[((s0 + rl)*BB + b)*H + col[n]] = hn;
                        cfin[((s0 + rl)*BB + b)*H + col[n]] = cn;
                    }
                }
            }
        __syncthreads();   // writes visible before next step's fragment reads
    }
}

extern "C" void kernel_launch(void* const* d_in, const int* in_sizes, int n_in,
                              void* d_out, int out_size, void* d_ws, size_t ws_size,
                              hipStream_t stream)
{
    const float* x    = (const float*)d_in[0];
    const float* W_fx = (const float*)d_in[1];
    const float* b_fx = (const float*)d_in[2];
    const float* W_fh = (const float*)d_in[3];
    const float* b_fh = (const float*)d_in[4];
    const float* W_cx = (const float*)d_in[5];
    const float* b_cx = (const float*)d_in[6];
    const float* W_ch = (const float*)d_in[7];
    const float* b_ch = (const float*)d_in[8];
    float* out = (float*)d_out;
    float* ws  = (float*)d_ws;

    float* fx = ws + FX_OFF;
    float* cx = ws + CX_OFF;
    ushort_t* wrp = (ushort_t*)(ws + WREP_OFF);

    hipLaunchKernelGGL(proj_kernel, dim3(ROWS), dim3(H), 0, stream,
                       x, W_fx, b_fx, W_cx, b_cx, fx, cx);
    hipLaunchKernelGGL(repack_kernel, dim3(H*H/256), dim3(256), 0, stream,
                       W_fh, W_ch, wrp);
    hipLaunchKernelGGL(lstm_mfma_kernel, dim3(NB), dim3(512), 0, stream,
                       fx, cx, wrp, b_fh, b_ch, out);
}